// Round 4
// baseline (210.566 us; speedup 1.0000x reference)
//
#include <hip/hip_runtime.h>
#include <hip/hip_bf16.h>

typedef __bf16 bf16_t;
typedef bf16_t bf16x8 __attribute__((ext_vector_type(8)));
typedef float f32x4 __attribute__((ext_vector_type(4)));

#define NB 2
#define SEQ 2048
#define DIM 1024
#define NH 32
#define HDIM 32

#define LDP 72  // attn P-tile LDS row stride (144B: 16B-aligned, b128 reads conflict-free)

static __device__ __forceinline__ f32x4 mfma16(bf16x8 a, bf16x8 b, f32x4 c) {
    return __builtin_amdgcn_mfma_f32_16x16x32_bf16(a, b, c, 0, 0, 0);
}

// raw v_exp_f32: computes 2^x. log2(e) is pre-folded into the Q scale.
static __device__ __forceinline__ float fexp2(float x) {
    float r;
    asm("v_exp_f32 %0, %1" : "=v"(r) : "v"(x));
    return r;
}

// async global->LDS, 16B per lane; lds dest = wave-uniform base + lane*16
static __device__ __forceinline__ void load_lds16(const bf16_t* g, bf16_t* l) {
    __builtin_amdgcn_global_load_lds(
        (const __attribute__((address_space(1))) void*)(g),
        (__attribute__((address_space(3))) void*)(l), 16, 0, 0);
}

// ---------------------------------------------------------------------------
// fp32 -> bf16 convert. 5 regions (x, wq, wk, wv, wo), grid-stride.
// ---------------------------------------------------------------------------
__global__ __launch_bounds__(256)
void cvt_f32_bf16(const float* __restrict__ s0, bf16_t* __restrict__ d0, int n0,
                  const float* __restrict__ s1, bf16_t* __restrict__ d1, int n1,
                  const float* __restrict__ s2, bf16_t* __restrict__ d2, int n2,
                  const float* __restrict__ s3, bf16_t* __restrict__ d3, int n3,
                  const float* __restrict__ s4, bf16_t* __restrict__ d4, int n4) {
    const int stride = gridDim.x * blockDim.x;
    const int tid = blockIdx.x * blockDim.x + threadIdx.x;
    const float* src[5] = {s0, s1, s2, s3, s4};
    bf16_t* dst[5] = {d0, d1, d2, d3, d4};
    const int n[5] = {n0, n1, n2, n3, n4};
#pragma unroll
    for (int r = 0; r < 5; r++) {
        const int nv = n[r] >> 2;
        for (int i = tid; i < nv; i += stride) {
            float4 v = ((const float4*)src[r])[i];
            bf16_t o[4] = {(bf16_t)v.x, (bf16_t)v.y, (bf16_t)v.z, (bf16_t)v.w};
            *(uint2*)(dst[r] + i * 4) = *(const uint2*)o;
        }
    }
}

// ---------------------------------------------------------------------------
// Pipelined GEMM: C = A @ W^T, all-bf16, BN=128, BK=32.
// TRIPLE-buffered LDS (stage k+2 ahead, steady-state vmcnt(8)/(6)). BOTH-SIDES
// XOR swizzle (q' = q ^ ((row>>1)&3)) on global source + LDS read: kills the
// 8-way ds_read_b128 bank conflict of the row-major [*][32] tile.
// EPI 0 (BM=64): out-proj -> fp32 C. EPI 1 (BM=128): fused QKV:
//   seg0 -> qb PRE-SCALED by slen[s]*ss[h]*log2(e)/sqrt(32), seg1 -> kb
//   (4-STRIDED key permutation to match attn's K-tile layout is NOT needed:
//    attn reads K rows directly), seg2 -> vtb (transposed store).
// XCD-swizzled 1-D grid (id&7 = XCD).
// ---------------------------------------------------------------------------
template <int EPI, int BM>
__global__ __launch_bounds__(256)
void gemm_pipe(const bf16_t* __restrict__ A, const bf16_t* __restrict__ W,
               float* __restrict__ Cf, bf16_t* __restrict__ qb,
               bf16_t* __restrict__ kb, bf16_t* __restrict__ vtb,
               const float* __restrict__ slen, const float* __restrict__ ss) {
    constexpr int MI = BM / 32;      // m-frags per wave
    constexpr int ABUF = BM * 32;    // elems per A stage buffer
    __shared__ alignas(16) bf16_t As[3 * ABUF];
    __shared__ alignas(16) bf16_t Bs[3 * 4096];
    const int t = threadIdx.x;
    const int lane = t & 63, wave = t >> 6;
    const int lane16 = lane & 15, quad = lane >> 4;
    const int wm = (wave >> 1) * (BM / 2), wn = (wave & 1) * 64;
    const int id = blockIdx.x;
    int m0, n0g;
    if (EPI == 1) {  // 768 = 8 xcd * 4 mslot * 24 n
        const int xcd = id & 7, slot = id >> 3;
        m0 = (xcd + 8 * (slot & 3)) * 128;
        n0g = (slot >> 2) * 128;
    } else {  // 512 = 8 xcd * 8 mslot * 8 n
        const int xcd = id & 7, slot = id >> 3;
        m0 = (xcd + 8 * (slot & 7)) * 64;
        n0g = (slot >> 3) * 128;
    }
    const int tr = t >> 2;                        // 0..63 (LDS chunk row)
    const int tc = ((t & 3) ^ ((tr >> 1) & 3)) * 8;  // SWIZZLED source quad
    const bf16_t* ga = A + (m0 + tr) * DIM + tc;
    const bf16_t* gb = W + (n0g + tr) * DIM + tc;
    const int rq = (quad ^ ((lane16 >> 1) & 3)) * 8;  // read-side involution
    const bool vseg = (EPI == 1) && (n0g >= 2048);

    f32x4 acc[MI][4];
#pragma unroll
    for (int i = 0; i < MI; i++)
#pragma unroll
        for (int j = 0; j < 4; j++) acc[i][j] = f32x4{0.f, 0.f, 0.f, 0.f};

    auto stage = [&](int k0, int buf) {
        bf16_t* a_dst = As + buf * ABUF + (t & 192) * 8;
        bf16_t* b_dst = Bs + buf * 4096 + (t & 192) * 8;
        load_lds16(ga + k0, a_dst);
        if (BM == 128) load_lds16(ga + 64 * DIM + k0, a_dst + 2048);
        load_lds16(gb + k0, b_dst);
        load_lds16(gb + 64 * DIM + k0, b_dst + 2048);
    };
    auto compute = [&](int buf) {
        bf16x8 af[MI], bfr[4];
#pragma unroll
        for (int mi = 0; mi < MI; mi++)
            af[mi] = *(const bf16x8*)(As + buf * ABUF +
                                      (wm + mi * 16 + lane16) * 32 + rq);
#pragma unroll
        for (int ni = 0; ni < 4; ni++)
            bfr[ni] = *(const bf16x8*)(Bs + buf * 4096 +
                                       (wn + ni * 16 + lane16) * 32 + rq);
        if (vseg) {
#pragma unroll
            for (int mi = 0; mi < MI; mi++)
#pragma unroll
                for (int ni = 0; ni < 4; ni++)
                    acc[mi][ni] = mfma16(bfr[ni], af[mi], acc[mi][ni]);
        } else {
#pragma unroll
            for (int mi = 0; mi < MI; mi++)
#pragma unroll
                for (int ni = 0; ni < 4; ni++)
                    acc[mi][ni] = mfma16(af[mi], bfr[ni], acc[mi][ni]);
        }
    };

    stage(0, 0);
    stage(32, 1);
#pragma unroll
    for (int k0 = 0; k0 < DIM; k0 += 32) {
        const int it = k0 >> 5;
        const int cur = it % 3;
        if (k0 + 64 < DIM) {
            stage(k0 + 64, (it + 2) % 3);
            if (BM == 128)
                asm volatile("s_waitcnt vmcnt(8)" ::: "memory");
            else
                asm volatile("s_waitcnt vmcnt(6)" ::: "memory");
        } else if (k0 + 32 < DIM) {
            if (BM == 128)
                asm volatile("s_waitcnt vmcnt(4)" ::: "memory");
            else
                asm volatile("s_waitcnt vmcnt(3)" ::: "memory");
        } else {
            asm volatile("s_waitcnt vmcnt(0)" ::: "memory");
        }
        asm volatile("s_barrier" ::: "memory");
        compute(cur);
        if (k0 + 32 < DIM) {
            asm volatile("s_waitcnt lgkmcnt(0)" ::: "memory");
            asm volatile("s_barrier" ::: "memory");  // reads done; safe to overwrite
        }
    }

    if (EPI == 0) {
#pragma unroll
        for (int mi = 0; mi < MI; mi++)
#pragma unroll
            for (int ni = 0; ni < 4; ni++)
#pragma unroll
                for (int r = 0; r < 4; r++) {
                    int row = m0 + wm + mi * 16 + quad * 4 + r;
                    int col = n0g + wn + ni * 16 + lane16;
                    Cf[row * DIM + col] = acc[mi][ni][r];
                }
    } else if (!vseg) {
        const bool isq = (n0g < 1024);
        bf16_t* dst = isq ? qb : kb;
        const int nb = n0g & 1023;
#pragma unroll
        for (int mi = 0; mi < MI; mi++)
#pragma unroll
            for (int ni = 0; ni < 4; ni++) {
                const int h = ((nb + wn) >> 5) + (ni >> 1);  // lane-uniform
                // 1/sqrt(32) * log2(e): attn uses v_exp_f32 (2^x) directly
                const float hscale =
                    isq ? ss[h] * (0.17677669529663687f * 1.4426950408889634f)
                        : 0.f;
#pragma unroll
                for (int r = 0; r < 4; r++) {
                    int m = m0 + wm + mi * 16 + quad * 4 + r;  // b*SEQ+s
                    int nl = nb + wn + ni * 16 + lane16;       // h*HDIM+hd
                    int b = m >> 11, s = m & (SEQ - 1);
                    int d = nl & 31;
                    float v = acc[mi][ni][r];
                    if (isq) v *= slen[s] * hscale;  // folded SSMax scale
                    dst[(((b * NH + h) << 11) + s) * 32 + d] = (bf16_t)v;
                }
            }
    } else {  // V: acc = C^T tile; row(quad,r)=n(hd), col(lane16)=m(s)
        const int nb = n0g & 1023;
#pragma unroll
        for (int mi = 0; mi < MI; mi++)
#pragma unroll
            for (int ni = 0; ni < 4; ni++)
#pragma unroll
                for (int r = 0; r < 4; r++) {
                    int nl = nb + wn + ni * 16 + quad * 4 + r;  // h*HDIM+hd
                    int m = m0 + wm + mi * 16 + lane16;         // b*SEQ+s
                    int b = m >> 11, s = m & (SEQ - 1);
                    int h = nl >> 5, d = nl & 31;
                    vtb[(((b * NH + h) << 5) + d) * SEQ + s] = (bf16_t)acc[mi][ni][r];
                }
    }
}

// ---------------------------------------------------------------------------
// Flash attention, causal, SSMax+log2e PRE-FOLDED INTO Q (v_exp_f32 = 2^x).
// No online max. KVBLK=64: half the iterations of the KVBLK=32 version --
// the per-iteration fixed latency (MFMA->exp, LDS round-trip, load waits) is
// paid half as often (R1/R3 showed the kernel is chain-length-bound, not
// occupancy- or throughput-bound). Body order: pv(i-1) FIRST (V regs then
// reused for V(i): single V set), K consumed then immediately re-issued -> all
// waits counted, never vmcnt(0). K rows 4-STRIDED per score tile (tile t =
// physical keys 4*l16+t) so each lane's 4 P-values are contiguous LDS cols.
// P double-buffered in LDS, reads issued before overwriting writes.
// l via ones-column MFMA. 1024 blocks, 1 wave/q-tile, zigzag pairing.
// ---------------------------------------------------------------------------
__global__ __launch_bounds__(256, 4)
void attn_fwd(const bf16_t* __restrict__ q, const bf16_t* __restrict__ k,
              const bf16_t* __restrict__ vt, bf16_t* __restrict__ out) {
    __shared__ alignas(16) bf16_t pscr[4][2][32 * LDP];  // 36 KB
    const int t = threadIdx.x;
    const int lane = t & 63, wave = t >> 6;
    const int lane16 = lane & 15, quad = lane >> 4;
    const int gw = blockIdx.x * 4 + wave;  // 0..4095
    const int idx = gw & 63;
    const int qt = (idx & 1) ? (63 - (idx >> 1)) : (idx >> 1);
    const int h = (gw >> 6) & (NH - 1);
    const int b = gw >> 11;
    const int q0 = qt * 32;
    const bf16_t* qh = q + (b * NH + h) * SEQ * HDIM;
    const bf16_t* kh = k + (b * NH + h) * SEQ * HDIM;
    const bf16_t* vth = vt + (b * NH + h) * HDIM * SEQ;

    // P LDS: write row = mi*16+quad*4+r, col = 4*l16 + {0..3} (tile t = col%4);
    // read row = lane16 (+16), cols quad*8..+7 (+32 for key-half 1).
    bf16_t* wb0 = pscr[wave][0] + quad * 4 * LDP + 4 * lane16;
    bf16_t* wb1 = pscr[wave][1] + quad * 4 * LDP + 4 * lane16;
    const bf16_t* rb0 = pscr[wave][0] + lane16 * LDP + quad * 8;
    const bf16_t* rb1 = pscr[wave][1] + lane16 * LDP + quad * 8;

    bf16x8 qf[2];
    qf[0] = *(const bf16x8*)(qh + (q0 + lane16) * HDIM + quad * 8);
    qf[1] = *(const bf16x8*)(qh + (q0 + 16 + lane16) * HDIM + quad * 8);

    bf16x8 ones;
#pragma unroll
    for (int j = 0; j < 8; j++) ones[j] = (bf16_t)1.0f;

    f32x4 o[2][2], ol[2];
#pragma unroll
    for (int mi = 0; mi < 2; mi++) {
        ol[mi] = f32x4{0.f, 0.f, 0.f, 0.f};
#pragma unroll
        for (int ni = 0; ni < 2; ni++) o[mi][ni] = f32x4{0.f, 0.f, 0.f, 0.f};
    }

    // K: 4-strided tiles; lane reads K rows 4*l16+t (t=0..3 via imm offset)
    const bf16_t* kptr = kh + (4 * lane16) * HDIM + quad * 8;
    const bf16_t* vpa = vth + lane16 * SEQ + quad * 8;
    const bf16_t* vpb = vth + (16 + lane16) * SEQ + quad * 8;

    const f32x4 zz = f32x4{0.f, 0.f, 0.f, 0.f};
    bf16x8 kc[4], vc[4], pf[2][2];

    const int nb64 = (qt >> 1) + 1;  // 64-wide kv blocks (last = diagonal)

    // qk round h (tiles t=2h, 2h+1), exp + write to LDS buffer wb
    auto qkexp = [&](int hh, bf16_t* wb, int kv, bool domask) {
        f32x4 sc[2][2];
        __builtin_amdgcn_s_setprio(1);
#pragma unroll
        for (int mi = 0; mi < 2; mi++)
#pragma unroll
            for (int j = 0; j < 2; j++)
                sc[mi][j] = mfma16(qf[mi], kc[2 * hh + j], zz);
        __builtin_amdgcn_s_setprio(0);
#pragma unroll
        for (int mi = 0; mi < 2; mi++)
#pragma unroll
            for (int r = 0; r < 4; r++) {
                float p0 = fexp2(sc[mi][0][r]);  // key kv+4*l16+2h
                float p1 = fexp2(sc[mi][1][r]);  // key kv+4*l16+2h+1
                if (domask) {
                    const int rowg = q0 + mi * 16 + quad * 4 + r;
                    if (kv + 4 * lane16 + 2 * hh > rowg) p0 = 0.f;
                    if (kv + 4 * lane16 + 2 * hh + 1 > rowg) p1 = 0.f;
                }
                bf16_t pb[2] = {(bf16_t)p0, (bf16_t)p1};
                *(unsigned int*)(wb + (mi * 16 + r) * LDP + 2 * hh) =
                    *(const unsigned int*)pb;
            }
    };
    auto ldk = [&]() {  // issue next K tile into kc (regs just consumed)
#pragma unroll
        for (int tt = 0; tt < 4; tt++) kc[tt] = *(const bf16x8*)(kptr + tt * HDIM);
        kptr += 64 * HDIM;
    };
    auto ldv = [&](int kv) {  // V(kv) -> vc
        vc[0] = *(const bf16x8*)(vpa + kv);
        vc[1] = *(const bf16x8*)(vpa + kv + 32);
        vc[2] = *(const bf16x8*)(vpb + kv);
        vc[3] = *(const bf16x8*)(vpb + kv + 32);
    };
    auto ldp = [&](const bf16_t* rb) {
#pragma unroll
        for (int mi = 0; mi < 2; mi++) {
            pf[mi][0] = *(const bf16x8*)(rb + mi * 16 * LDP);
            pf[mi][1] = *(const bf16x8*)(rb + mi * 16 * LDP + 32);
        }
    };
    auto pv = [&]() {
        __builtin_amdgcn_s_setprio(1);
#pragma unroll
        for (int mi = 0; mi < 2; mi++) {
#pragma unroll
            for (int ni = 0; ni < 2; ni++) {
                o[mi][ni] = mfma16(pf[mi][0], vc[2 * ni], o[mi][ni]);
                o[mi][ni] = mfma16(pf[mi][1], vc[2 * ni + 1], o[mi][ni]);
            }
            ol[mi] = mfma16(pf[mi][0], ones, ol[mi]);
            ol[mi] = mfma16(pf[mi][1], ones, ol[mi]);
        }
        __builtin_amdgcn_s_setprio(0);
    };

    // ---- prologue (block 0): K(0), V(0) in flight; qk+exp+write buf0
    ldk();          // K(0); kptr -> K(1)
    ldv(0);         // V(0)
    {
        const bool m0only = (nb64 == 1);
        qkexp(0, wb0, 0, m0only);
        bf16x8 ksave[4];  // consume kc, then refill with K(1)
        qkexp(1, wb0, 0, m0only);
        (void)ksave;
        ldk();      // K(1) (dead loads if nb64==1; in-bounds)
    }

    // ---- main loop i = 1..nb64-2 (no mask)
    for (int i = 1; i < nb64 - 1; i++) {
        const int kv = i << 6;
        bf16_t* wb = (i & 1) ? wb1 : wb0;
        const bf16_t* rb = (i & 1) ? rb0 : rb1;
        ldp(rb);        // P(i-1): in-order LDS, after prev writes
        pv();           // P(i-1) x V(i-1); vc regs now dead
        ldv(kv);        // V(i) into vc
        qkexp(0, wb, kv, false);   // waits kc via counted vmcnt
        qkexp(1, wb, kv, false);
        ldk();          // K(i+1)
    }

    // ---- tail i = nb64-1 (masked diagonal), if nb64 >= 2
    if (nb64 > 1) {
        const int i = nb64 - 1;
        const int kv = i << 6;
        bf16_t* wb = (i & 1) ? wb1 : wb0;
        const bf16_t* rb = (i & 1) ? rb0 : rb1;
        ldp(rb);
        pv();
        ldv(kv);
        qkexp(0, wb, kv, true);
        qkexp(1, wb, kv, true);
        // no K reload needed; keep branchless symmetry cheap by skipping it
    }

    // ---- epilogue: last P tile
    ldp(((nb64 - 1) & 1) ? rb1 : rb0);
    pv();

    // ---- normalize + store: l = ol[mi][r] (replicated across lane16)
#pragma unroll
    for (int mi = 0; mi < 2; mi++)
#pragma unroll
        for (int r = 0; r < 4; r++) {
            float inv = 1.0f / ol[mi][r];
            int qi = q0 + mi * 16 + quad * 4 + r;
            bf16_t* ob = out + (b * SEQ + qi) * DIM + h * HDIM;
            ob[lane16] = (bf16_t)(o[mi][0][r] * inv);
            ob[16 + lane16] = (bf16_t)(o[mi][1][r] * inv);
        }
}

extern "C" void kernel_launch(void* const* d_in, const int* in_sizes, int n_in,
                              void* d_out, int out_size, void* d_ws, size_t ws_size,
                              hipStream_t stream) {
    // input order: x, mask, section_log_len, wq, wk, wv, wo, seq_scale
    // dtype model (verified): fp32 I/O, bf16 internal compute.
    const float* x = (const float*)d_in[0];
    const float* slen = (const float*)d_in[2];
    const float* wq = (const float*)d_in[3];
    const float* wk = (const float*)d_in[4];
    const float* wv = (const float*)d_in[5];
    const float* wo = (const float*)d_in[6];
    const float* ss = (const float*)d_in[7];

    const size_t ELEMS = (size_t)NB * SEQ * DIM;  // 4 Mi elems
    const size_t WELEMS = (size_t)DIM * DIM;      // 1 Mi elems
    // ws layout (bf16 elems), 32 MB:
    bf16_t* xb = (bf16_t*)d_ws;           // phase 1: bf16 x
    bf16_t* abuf = xb;                    // phase 2: attn out
    bf16_t* wqkvb = xb + ELEMS;           // packed [wq;wk;wv], N=3072
    bf16_t* wob = wqkvb + 3 * WELEMS;
    bf16_t* qbuf = wob + WELEMS;          // (B,H,S,HD), PRE-SCALED (incl log2e)
    bf16_t* vtbuf = qbuf + ELEMS;         // (B,H,HD,S)
    bf16_t* kbuf = (bf16_t*)d_out;        // 8 MB of 16 MB fp32 out (scratch)

    dim3 blk(256);
    cvt_f32_bf16<<<dim3(1024), blk, 0, stream>>>(
        x, xb, (int)ELEMS, wq, wqkvb, (int)WELEMS, wk, wqkvb + WELEMS,
        (int)WELEMS, wv, wqkvb + 2 * WELEMS, (int)WELEMS, wo, wob, (int)WELEMS);

    // QKV: 768 blocks (3/CU), XCD-swizzled, 3-deep pipelined K-loop, swizzled LDS
    gemm_pipe<1, 128><<<dim3(768), blk, 0, stream>>>(
        xb, wqkvb, nullptr, qbuf, kbuf, vtbuf, slen, ss);
    // attn: 1024 blocks, 1 wave per q-tile, KVBLK=64, software-pipelined P
    attn_fwd<<<dim3(NB * NH * (SEQ / 32) / 4), blk, 0, stream>>>(
        qbuf, kbuf, vtbuf, abuf);
    // out-proj: 512 blocks (2/CU), XCD-swizzled, 3-deep pipelined K-loop
    gemm_pipe<0, 64><<<dim3(512), blk, 0, stream>>>(
        abuf, wob, (float*)d_out, nullptr, nullptr, nullptr, nullptr, nullptr);
}

// Round 6
// 209.648 us; speedup vs baseline: 1.0044x; 1.0044x over previous
//
#include <hip/hip_runtime.h>
#include <hip/hip_bf16.h>

typedef __bf16 bf16_t;
typedef bf16_t bf16x8 __attribute__((ext_vector_type(8)));
typedef float f32x4 __attribute__((ext_vector_type(4)));

#define NB 2
#define SEQ 2048
#define DIM 1024
#define NH 32
#define HDIM 32

#define LDP 72  // attn P-tile LDS row stride (144B: 16B-aligned, b128 reads conflict-free)

static __device__ __forceinline__ f32x4 mfma16(bf16x8 a, bf16x8 b, f32x4 c) {
    return __builtin_amdgcn_mfma_f32_16x16x32_bf16(a, b, c, 0, 0, 0);
}

// raw v_exp_f32: computes 2^x. log2(e) is pre-folded into the Q scale.
static __device__ __forceinline__ float fexp2(float x) {
    float r;
    asm("v_exp_f32 %0, %1" : "=v"(r) : "v"(x));
    return r;
}

// async global->LDS, 16B per lane; lds dest = wave-uniform base + lane*16
static __device__ __forceinline__ void load_lds16(const bf16_t* g, bf16_t* l) {
    __builtin_amdgcn_global_load_lds(
        (const __attribute__((address_space(1))) void*)(g),
        (__attribute__((address_space(3))) void*)(l), 16, 0, 0);
}

// ---------------------------------------------------------------------------
// fp32 -> bf16 convert. 5 regions (x, wq, wk, wv, wo), grid-stride.
// ---------------------------------------------------------------------------
__global__ __launch_bounds__(256)
void cvt_f32_bf16(const float* __restrict__ s0, bf16_t* __restrict__ d0, int n0,
                  const float* __restrict__ s1, bf16_t* __restrict__ d1, int n1,
                  const float* __restrict__ s2, bf16_t* __restrict__ d2, int n2,
                  const float* __restrict__ s3, bf16_t* __restrict__ d3, int n3,
                  const float* __restrict__ s4, bf16_t* __restrict__ d4, int n4) {
    const int stride = gridDim.x * blockDim.x;
    const int tid = blockIdx.x * blockDim.x + threadIdx.x;
    const float* src[5] = {s0, s1, s2, s3, s4};
    bf16_t* dst[5] = {d0, d1, d2, d3, d4};
    const int n[5] = {n0, n1, n2, n3, n4};
#pragma unroll
    for (int r = 0; r < 5; r++) {
        const int nv = n[r] >> 2;
        for (int i = tid; i < nv; i += stride) {
            float4 v = ((const float4*)src[r])[i];
            bf16_t o[4] = {(bf16_t)v.x, (bf16_t)v.y, (bf16_t)v.z, (bf16_t)v.w};
            *(uint2*)(dst[r] + i * 4) = *(const uint2*)o;
        }
    }
}

// ---------------------------------------------------------------------------
// Pipelined GEMM: C = A @ W^T, all-bf16, BN=128, BK=32.
// TRIPLE-buffered LDS (stage k+2 ahead, steady-state vmcnt(8)/(6)). BOTH-SIDES
// XOR swizzle (q' = q ^ ((row>>1)&3)) on global source + LDS read: kills the
// 8-way ds_read_b128 bank conflict of the row-major [*][32] tile.
// EPI 0 (BM=64): out-proj -> fp32 C. EPI 1 (BM=128): fused QKV:
//   seg0 -> qb PRE-SCALED by slen[s]*ss[h]*log2(e)/sqrt(32), seg1 -> kb,
//   seg2 -> vtb (transposed store). XCD-swizzled 1-D grid (id&7 = XCD).
// ---------------------------------------------------------------------------
template <int EPI, int BM>
__global__ __launch_bounds__(256)
void gemm_pipe(const bf16_t* __restrict__ A, const bf16_t* __restrict__ W,
               float* __restrict__ Cf, bf16_t* __restrict__ qb,
               bf16_t* __restrict__ kb, bf16_t* __restrict__ vtb,
               const float* __restrict__ slen, const float* __restrict__ ss) {
    constexpr int MI = BM / 32;      // m-frags per wave
    constexpr int ABUF = BM * 32;    // elems per A stage buffer
    __shared__ alignas(16) bf16_t As[3 * ABUF];
    __shared__ alignas(16) bf16_t Bs[3 * 4096];
    const int t = threadIdx.x;
    const int lane = t & 63, wave = t >> 6;
    const int lane16 = lane & 15, quad = lane >> 4;
    const int wm = (wave >> 1) * (BM / 2), wn = (wave & 1) * 64;
    const int id = blockIdx.x;
    int m0, n0g;
    if (EPI == 1) {  // 768 = 8 xcd * 4 mslot * 24 n
        const int xcd = id & 7, slot = id >> 3;
        m0 = (xcd + 8 * (slot & 3)) * 128;
        n0g = (slot >> 2) * 128;
    } else {  // 512 = 8 xcd * 8 mslot * 8 n
        const int xcd = id & 7, slot = id >> 3;
        m0 = (xcd + 8 * (slot & 7)) * 64;
        n0g = (slot >> 3) * 128;
    }
    const int tr = t >> 2;                        // 0..63 (LDS chunk row)
    const int tc = ((t & 3) ^ ((tr >> 1) & 3)) * 8;  // SWIZZLED source quad
    const bf16_t* ga = A + (m0 + tr) * DIM + tc;
    const bf16_t* gb = W + (n0g + tr) * DIM + tc;
    const int rq = (quad ^ ((lane16 >> 1) & 3)) * 8;  // read-side involution
    const bool vseg = (EPI == 1) && (n0g >= 2048);

    f32x4 acc[MI][4];
#pragma unroll
    for (int i = 0; i < MI; i++)
#pragma unroll
        for (int j = 0; j < 4; j++) acc[i][j] = f32x4{0.f, 0.f, 0.f, 0.f};

    auto stage = [&](int k0, int buf) {
        bf16_t* a_dst = As + buf * ABUF + (t & 192) * 8;
        bf16_t* b_dst = Bs + buf * 4096 + (t & 192) * 8;
        load_lds16(ga + k0, a_dst);
        if (BM == 128) load_lds16(ga + 64 * DIM + k0, a_dst + 2048);
        load_lds16(gb + k0, b_dst);
        load_lds16(gb + 64 * DIM + k0, b_dst + 2048);
    };
    auto compute = [&](int buf) {
        bf16x8 af[MI], bfr[4];
#pragma unroll
        for (int mi = 0; mi < MI; mi++)
            af[mi] = *(const bf16x8*)(As + buf * ABUF +
                                      (wm + mi * 16 + lane16) * 32 + rq);
#pragma unroll
        for (int ni = 0; ni < 4; ni++)
            bfr[ni] = *(const bf16x8*)(Bs + buf * 4096 +
                                       (wn + ni * 16 + lane16) * 32 + rq);
        if (vseg) {
#pragma unroll
            for (int mi = 0; mi < MI; mi++)
#pragma unroll
                for (int ni = 0; ni < 4; ni++)
                    acc[mi][ni] = mfma16(bfr[ni], af[mi], acc[mi][ni]);
        } else {
#pragma unroll
            for (int mi = 0; mi < MI; mi++)
#pragma unroll
                for (int ni = 0; ni < 4; ni++)
                    acc[mi][ni] = mfma16(af[mi], bfr[ni], acc[mi][ni]);
        }
    };

    stage(0, 0);
    stage(32, 1);
#pragma unroll
    for (int k0 = 0; k0 < DIM; k0 += 32) {
        const int it = k0 >> 5;
        const int cur = it % 3;
        if (k0 + 64 < DIM) {
            stage(k0 + 64, (it + 2) % 3);
            if (BM == 128)
                asm volatile("s_waitcnt vmcnt(8)" ::: "memory");
            else
                asm volatile("s_waitcnt vmcnt(6)" ::: "memory");
        } else if (k0 + 32 < DIM) {
            if (BM == 128)
                asm volatile("s_waitcnt vmcnt(4)" ::: "memory");
            else
                asm volatile("s_waitcnt vmcnt(3)" ::: "memory");
        } else {
            asm volatile("s_waitcnt vmcnt(0)" ::: "memory");
        }
        asm volatile("s_barrier" ::: "memory");
        compute(cur);
        if (k0 + 32 < DIM) {
            asm volatile("s_waitcnt lgkmcnt(0)" ::: "memory");
            asm volatile("s_barrier" ::: "memory");  // reads done; safe to overwrite
        }
    }

    if (EPI == 0) {
#pragma unroll
        for (int mi = 0; mi < MI; mi++)
#pragma unroll
            for (int ni = 0; ni < 4; ni++)
#pragma unroll
                for (int r = 0; r < 4; r++) {
                    int row = m0 + wm + mi * 16 + quad * 4 + r;
                    int col = n0g + wn + ni * 16 + lane16;
                    Cf[row * DIM + col] = acc[mi][ni][r];
                }
    } else if (!vseg) {
        const bool isq = (n0g < 1024);
        bf16_t* dst = isq ? qb : kb;
        const int nb = n0g & 1023;
#pragma unroll
        for (int mi = 0; mi < MI; mi++)
#pragma unroll
            for (int ni = 0; ni < 4; ni++) {
                const int h = ((nb + wn) >> 5) + (ni >> 1);  // lane-uniform
                // 1/sqrt(32) * log2(e): attn uses v_exp_f32 (2^x) directly
                const float hscale =
                    isq ? ss[h] * (0.17677669529663687f * 1.4426950408889634f)
                        : 0.f;
#pragma unroll
                for (int r = 0; r < 4; r++) {
                    int m = m0 + wm + mi * 16 + quad * 4 + r;  // b*SEQ+s
                    int nl = nb + wn + ni * 16 + lane16;       // h*HDIM+hd
                    int b = m >> 11, s = m & (SEQ - 1);
                    int d = nl & 31;
                    float v = acc[mi][ni][r];
                    if (isq) v *= slen[s] * hscale;  // folded SSMax scale
                    dst[(((b * NH + h) << 11) + s) * 32 + d] = (bf16_t)v;
                }
            }
    } else {  // V: acc = C^T tile; row(quad,r)=n(hd), col(lane16)=m(s)
        const int nb = n0g & 1023;
#pragma unroll
        for (int mi = 0; mi < MI; mi++)
#pragma unroll
            for (int ni = 0; ni < 4; ni++)
#pragma unroll
                for (int r = 0; r < 4; r++) {
                    int nl = nb + wn + ni * 16 + quad * 4 + r;  // h*HDIM+hd
                    int m = m0 + wm + mi * 16 + lane16;         // b*SEQ+s
                    int b = m >> 11, s = m & (SEQ - 1);
                    int h = nl >> 5, d = nl & 31;
                    vtb[(((b * NH + h) << 5) + d) * SEQ + s] = (bf16_t)acc[mi][ni][r];
                }
    }
}

// ---------------------------------------------------------------------------
// Flash attention, causal, SSMax+log2e PRE-FOLDED INTO Q (v_exp_f32 = 2^x).
// No online max. KVBLK=64, software-pipelined P (double-buffered LDS),
// l via ones-column MFMA. COMPLEMENT-PAIRED per-SIMD balance: 512 blocks x
// 512 threads (8 waves). All 8 waves share one (b,h) = blockIdx>>3; wave w
// takes tile tb = (blockIdx&7)*4 + (w&3) if w<4, else its complement 63-tb.
// Waves w and w+4 sit on the same SIMD (w mod 4) and iters(t)+iters(63-t)=33
// IDENTICALLY -> every SIMD gets 66 iterations regardless of dispatch order
// (R4's zigzag put 128 iters on odd SIMDs, ~8 on even ones). Bijective over
// (bh, qt) trivially. 8 waves stream the same head's K/V -> L2 sharing.
// LDS 72KB/block -> 2 blocks/CU (144 <= 160KB), 16 waves/CU.
// ---------------------------------------------------------------------------
__global__ __launch_bounds__(512, 4)
void attn_fwd(const bf16_t* __restrict__ q, const bf16_t* __restrict__ k,
              const bf16_t* __restrict__ vt, bf16_t* __restrict__ out) {
    __shared__ alignas(16) bf16_t pscr[8][2][32 * LDP];  // 72 KB
    const int t = threadIdx.x;
    const int lane = t & 63, wave = t >> 6;  // wave 0..7
    const int lane16 = lane & 15, quad = lane >> 4;
    // complement-paired work map (dispatch-agnostic per-SIMD balance)
    const int g = blockIdx.x & 7;
    const int bh = blockIdx.x >> 3;          // 0..63
    const int tb = g * 4 + (wave & 3);       // 0..31
    const int qt = (wave < 4) ? tb : (63 - tb);
    const int h = bh & (NH - 1);
    const int b = bh >> 5;
    const int q0 = qt * 32;
    const bf16_t* qh = q + (b * NH + h) * SEQ * HDIM;
    const bf16_t* kh = k + (b * NH + h) * SEQ * HDIM;
    const bf16_t* vth = vt + (b * NH + h) * HDIM * SEQ;

    // P LDS: write row = mi*16+quad*4+r, col = 4*l16 + {0..3} (tile t = col%4);
    // read row = lane16 (+16), cols quad*8..+7 (+32 for key-half 1).
    bf16_t* wb0 = pscr[wave][0] + quad * 4 * LDP + 4 * lane16;
    bf16_t* wb1 = pscr[wave][1] + quad * 4 * LDP + 4 * lane16;
    const bf16_t* rb0 = pscr[wave][0] + lane16 * LDP + quad * 8;
    const bf16_t* rb1 = pscr[wave][1] + lane16 * LDP + quad * 8;

    bf16x8 qf[2];
    qf[0] = *(const bf16x8*)(qh + (q0 + lane16) * HDIM + quad * 8);
    qf[1] = *(const bf16x8*)(qh + (q0 + 16 + lane16) * HDIM + quad * 8);

    bf16x8 ones;
#pragma unroll
    for (int j = 0; j < 8; j++) ones[j] = (bf16_t)1.0f;

    f32x4 o[2][2], ol[2];
#pragma unroll
    for (int mi = 0; mi < 2; mi++) {
        ol[mi] = f32x4{0.f, 0.f, 0.f, 0.f};
#pragma unroll
        for (int ni = 0; ni < 2; ni++) o[mi][ni] = f32x4{0.f, 0.f, 0.f, 0.f};
    }

    // K: 4-strided tiles; lane reads K rows 4*l16+t (t=0..3 via imm offset)
    const bf16_t* kptr = kh + (4 * lane16) * HDIM + quad * 8;
    const bf16_t* vpa = vth + lane16 * SEQ + quad * 8;
    const bf16_t* vpb = vth + (16 + lane16) * SEQ + quad * 8;

    const f32x4 zz = f32x4{0.f, 0.f, 0.f, 0.f};
    bf16x8 kc[4], vc[4], pf[2][2];

    const int nb64 = (qt >> 1) + 1;  // 64-wide kv blocks (last = diagonal)

    // qk round h (tiles t=2h, 2h+1), exp + write to LDS buffer wb
    auto qkexp = [&](int hh, bf16_t* wb, int kv, bool domask) {
        f32x4 sc[2][2];
        __builtin_amdgcn_s_setprio(1);
#pragma unroll
        for (int mi = 0; mi < 2; mi++)
#pragma unroll
            for (int j = 0; j < 2; j++)
                sc[mi][j] = mfma16(qf[mi], kc[2 * hh + j], zz);
        __builtin_amdgcn_s_setprio(0);
#pragma unroll
        for (int mi = 0; mi < 2; mi++)
#pragma unroll
            for (int r = 0; r < 4; r++) {
                float p0 = fexp2(sc[mi][0][r]);  // key kv+4*l16+2h
                float p1 = fexp2(sc[mi][1][r]);  // key kv+4*l16+2h+1
                if (domask) {
                    const int rowg = q0 + mi * 16 + quad * 4 + r;
                    if (kv + 4 * lane16 + 2 * hh > rowg) p0 = 0.f;
                    if (kv + 4 * lane16 + 2 * hh + 1 > rowg) p1 = 0.f;
                }
                bf16_t pb[2] = {(bf16_t)p0, (bf16_t)p1};
                *(unsigned int*)(wb + (mi * 16 + r) * LDP + 2 * hh) =
                    *(const unsigned int*)pb;
            }
    };
    auto ldk = [&]() {  // issue next K tile into kc (regs just consumed)
#pragma unroll
        for (int tt = 0; tt < 4; tt++) kc[tt] = *(const bf16x8*)(kptr + tt * HDIM);
        kptr += 64 * HDIM;
    };
    auto ldv = [&](int kv) {  // V(kv) -> vc
        vc[0] = *(const bf16x8*)(vpa + kv);
        vc[1] = *(const bf16x8*)(vpa + kv + 32);
        vc[2] = *(const bf16x8*)(vpb + kv);
        vc[3] = *(const bf16x8*)(vpb + kv + 32);
    };
    auto ldp = [&](const bf16_t* rb) {
#pragma unroll
        for (int mi = 0; mi < 2; mi++) {
            pf[mi][0] = *(const bf16x8*)(rb + mi * 16 * LDP);
            pf[mi][1] = *(const bf16x8*)(rb + mi * 16 * LDP + 32);
        }
    };
    auto pv = [&]() {
        __builtin_amdgcn_s_setprio(1);
#pragma unroll
        for (int mi = 0; mi < 2; mi++) {
#pragma unroll
            for (int ni = 0; ni < 2; ni++) {
                o[mi][ni] = mfma16(pf[mi][0], vc[2 * ni], o[mi][ni]);
                o[mi][ni] = mfma16(pf[mi][1], vc[2 * ni + 1], o[mi][ni]);
            }
            ol[mi] = mfma16(pf[mi][0], ones, ol[mi]);
            ol[mi] = mfma16(pf[mi][1], ones, ol[mi]);
        }
        __builtin_amdgcn_s_setprio(0);
    };

    // ---- prologue (block 0): K(0), V(0) in flight; qk+exp+write buf0
    ldk();          // K(0); kptr -> K(1)
    ldv(0);         // V(0)
    {
        const bool m0only = (nb64 == 1);
        qkexp(0, wb0, 0, m0only);
        bf16x8 ksave[4];  // consume kc, then refill with K(1)
        qkexp(1, wb0, 0, m0only);
        (void)ksave;
        ldk();      // K(1) (dead loads if nb64==1; in-bounds)
    }

    // ---- main loop i = 1..nb64-2 (no mask)
    for (int i = 1; i < nb64 - 1; i++) {
        const int kv = i << 6;
        bf16_t* wb = (i & 1) ? wb1 : wb0;
        const bf16_t* rb = (i & 1) ? rb0 : rb1;
        ldp(rb);        // P(i-1): in-order LDS, after prev writes
        pv();           // P(i-1) x V(i-1); vc regs now dead
        ldv(kv);        // V(i) into vc
        qkexp(0, wb, kv, false);   // waits kc via counted vmcnt
        qkexp(1, wb, kv, false);
        ldk();          // K(i+1)
    }

    // ---- tail i = nb64-1 (masked diagonal), if nb64 >= 2
    if (nb64 > 1) {
        const int i = nb64 - 1;
        const int kv = i << 6;
        bf16_t* wb = (i & 1) ? wb1 : wb0;
        const bf16_t* rb = (i & 1) ? rb0 : rb1;
        ldp(rb);
        pv();
        ldv(kv);
        qkexp(0, wb, kv, true);
        qkexp(1, wb, kv, true);
    }

    // ---- epilogue: last P tile
    ldp(((nb64 - 1) & 1) ? rb1 : rb0);
    pv();

    // ---- normalize + store: l = ol[mi][r] (replicated across lane16)
#pragma unroll
    for (int mi = 0; mi < 2; mi++)
#pragma unroll
        for (int r = 0; r < 4; r++) {
            float inv = 1.0f / ol[mi][r];
            int qi = q0 + mi * 16 + quad * 4 + r;
            bf16_t* ob = out + (b * SEQ + qi) * DIM + h * HDIM;
            ob[lane16] = (bf16_t)(o[mi][0][r] * inv);
            ob[16 + lane16] = (bf16_t)(o[mi][1][r] * inv);
        }
}

extern "C" void kernel_launch(void* const* d_in, const int* in_sizes, int n_in,
                              void* d_out, int out_size, void* d_ws, size_t ws_size,
                              hipStream_t stream) {
    // input order: x, mask, section_log_len, wq, wk, wv, wo, seq_scale
    // dtype model (verified): fp32 I/O, bf16 internal compute.
    const float* x = (const float*)d_in[0];
    const float* slen = (const float*)d_in[2];
    const float* wq = (const float*)d_in[3];
    const float* wk = (const float*)d_in[4];
    const float* wv = (const float*)d_in[5];
    const float* wo = (const float*)d_in[6];
    const float* ss = (const float*)d_in[7];

    const size_t ELEMS = (size_t)NB * SEQ * DIM;  // 4 Mi elems
    const size_t WELEMS = (size_t)DIM * DIM;      // 1 Mi elems
    // ws layout (bf16 elems), 32 MB:
    bf16_t* xb = (bf16_t*)d_ws;           // phase 1: bf16 x
    bf16_t* abuf = xb;                    // phase 2: attn out
    bf16_t* wqkvb = xb + ELEMS;           // packed [wq;wk;wv], N=3072
    bf16_t* wob = wqkvb + 3 * WELEMS;
    bf16_t* qbuf = wob + WELEMS;          // (B,H,S,HD), PRE-SCALED (incl log2e)
    bf16_t* vtbuf = qbuf + ELEMS;         // (B,H,HD,S)
    bf16_t* kbuf = (bf16_t*)d_out;        // 8 MB of 16 MB fp32 out (scratch)

    dim3 blk(256);
    cvt_f32_bf16<<<dim3(1024), blk, 0, stream>>>(
        x, xb, (int)ELEMS, wq, wqkvb, (int)WELEMS, wk, wqkvb + WELEMS,
        (int)WELEMS, wv, wqkvb + 2 * WELEMS, (int)WELEMS, wo, wob, (int)WELEMS);

    // QKV: 768 blocks (3/CU), XCD-swizzled, 3-deep pipelined K-loop, swizzled LDS
    gemm_pipe<1, 128><<<dim3(768), blk, 0, stream>>>(
        xb, wqkvb, nullptr, qbuf, kbuf, vtbuf, slen, ss);
    // attn: 512 blocks x 512 threads, complement-paired per-SIMD balance
    attn_fwd<<<dim3(NB * NH * (SEQ / 32) / 8), dim3(512), 0, stream>>>(
        qbuf, kbuf, vtbuf, abuf);
    // out-proj: 512 blocks (2/CU), XCD-swizzled, 3-deep pipelined K-loop
    gemm_pipe<0, 64><<<dim3(512), blk, 0, stream>>>(
        abuf, wob, (float*)d_out, nullptr, nullptr, nullptr, nullptr, nullptr);
}